// Round 1
// baseline (2023.219 us; speedup 1.0000x reference)
//
#include <hip/hip_runtime.h>
#include <math.h>

// Problem constants: B=4, TU=2048, TM=256, D=1024, H=16, DH=64, PAIRS=512
#define D_ 1024

__device__ __forceinline__ float sigmoidf_(float x) { return 1.0f / (1.0f + __expf(-x)); }

// ---------------------------------------------------------------------------
// balance_norm + gate: one block per row of 1024. Writes normed row and the
// sigmoid(row . gw + gb) gate scalar.
// ---------------------------------------------------------------------------
__global__ void __launch_bounds__(256) norm_gate_kernel(
    const float* __restrict__ X,
    const float* __restrict__ w, const float* __restrict__ bvec,
    const float* __restrict__ bw_p,
    const float* __restrict__ gw, const float* __restrict__ gb_p,
    float* __restrict__ OUT, float* __restrict__ G)
{
    const int row = blockIdx.x;
    const int t = threadIdx.x;
    const float* xr = X + (size_t)row * D_;
    float4 x4 = *(const float4*)(xr + 4 * t);
    __shared__ float sh1[256], sh2[256];
    sh1[t] = x4.x + x4.y + x4.z + x4.w;
    sh2[t] = x4.x * x4.x + x4.y * x4.y + x4.z * x4.z + x4.w * x4.w;
    __syncthreads();
    // per-half sums of x^2 (threads [0,128) own elems [0,512))
    for (int o = 64; o > 0; o >>= 1) {
        if ((t & 127) < o) sh2[t] += sh2[t + o];
        __syncthreads();
    }
    const float slo = sh2[0], shi = sh2[128];
    for (int o = 128; o > 0; o >>= 1) {
        if (t < o) sh1[t] += sh1[t + o];
        __syncthreads();
    }
    const float mu = sh1[0] * (1.0f / D_);
    const float var = (slo + shi) * (1.0f / D_) - mu * mu;
    const float rstd = rsqrtf(var + 1e-6f);
    const float imb = (slo - shi) * (1.0f / 512.0f) * (*bw_p);
    const float corr = (t < 128) ? -imb : imb;
    const int i0 = 4 * t;
    float o0 = (x4.x - mu) * rstd * w[i0 + 0] + bvec[i0 + 0] + corr;
    float o1 = (x4.y - mu) * rstd * w[i0 + 1] + bvec[i0 + 1] + corr;
    float o2 = (x4.z - mu) * rstd * w[i0 + 2] + bvec[i0 + 2] + corr;
    float o3 = (x4.w - mu) * rstd * w[i0 + 3] + bvec[i0 + 3] + corr;
    float gd = o0 * gw[i0 + 0] + o1 * gw[i0 + 1] + o2 * gw[i0 + 2] + o3 * gw[i0 + 3];
    __syncthreads();
    sh1[t] = gd;
    __syncthreads();
    for (int o = 128; o > 0; o >>= 1) {
        if (t < o) sh1[t] += sh1[t + o];
        __syncthreads();
    }
    if (t == 0) G[row] = sigmoidf_(sh1[0] + *gb_p);
    float4 o4; o4.x = o0; o4.y = o1; o4.z = o2; o4.w = o3;
    *(float4*)(OUT + (size_t)row * D_ + i0) = o4;
}

// ---------------------------------------------------------------------------
// Generic 64x64-tile fp32 GEMM, 256 threads, 4x4 per thread, BK=16.
// NT: C[m,n] = sum_k A[m*lda+k] * B[n*ldb+k]   (both K-contiguous)
// NN: C[m,n] = sum_k A[m*lda+k] * B[k*ldb+n]
// NORMAB: per-pair phase normalization of A/B elements during load.
// MODE 0: C = alpha*acc (or atomicAdd if ATOMIC)
// MODE 1: C = base + (alpha*acc)*rs[m]   (residual + row scale)
// MODE 2: resonance: v=alpha*acc; C = .7*accA + .3*v ; OT[n,m] = .7*accB[n,m]+.3*v
// z = blockIdx.z/nsplit selects batch/head slab; ks = blockIdx.z%nsplit splits K.
// ---------------------------------------------------------------------------
__device__ __forceinline__ float4 pairnorm4(float4 a)
{
    float px0 = a.x + 1e-8f, py0 = a.y + 1e-8f;
    float h0 = rsqrtf(px0 * px0 + py0 * py0);
    float px1 = a.z + 1e-8f, py1 = a.w + 1e-8f;
    float h1 = rsqrtf(px1 * px1 + py1 * py1);
    float4 r; r.x = px0 * h0; r.y = py0 * h0; r.z = px1 * h1; r.w = py1 * h1;
    return r;
}

template<int MODE, bool NORMAB, bool NN, bool ATOMIC>
__global__ void __launch_bounds__(256) gemm_kernel(
    const float* __restrict__ A, long zsA,
    const float* __restrict__ B, long zsB,
    float* __restrict__ C, long zsC,
    int K, int lda, int ldb, int ldc, float alpha,
    const float* __restrict__ base, const float* __restrict__ rs,
    const float* __restrict__ accA, long zsAA,
    const float* __restrict__ accB, long zsAB,
    float* __restrict__ OT, long zsOT, int ldt,
    int nsplit)
{
    __shared__ float As[16][68];
    __shared__ float Bs[16][68];
    const int t = threadIdx.x;
    const int tx = t & 15, ty = t >> 4;
    const int zz = blockIdx.z;
    const int z = zz / nsplit, ks = zz % nsplit;
    const int kchunk = K / nsplit;
    const int kbeg = ks * kchunk, kend = kbeg + kchunk;
    const int m0 = blockIdx.y * 64, n0 = blockIdx.x * 64;
    const float* Ab = A + (long)z * zsA + (long)m0 * lda;
    const float* Bb = NN ? (B + (long)z * zsB + n0)
                         : (B + (long)z * zsB + (long)n0 * ldb);
    const int lr = t >> 2, lk4 = (t & 3) * 4;     // NT loader: row, k-offset
    const int bkk = t >> 4, bn4 = (t & 15) * 4;   // NN B loader: k-row, n-offset
    float acc[4][4] = {};
    for (int k0 = kbeg; k0 < kend; k0 += 16) {
        float4 a4 = *(const float4*)(Ab + (long)lr * lda + (k0 + lk4));
        if (NORMAB) a4 = pairnorm4(a4);
        As[lk4 + 0][lr] = a4.x; As[lk4 + 1][lr] = a4.y;
        As[lk4 + 2][lr] = a4.z; As[lk4 + 3][lr] = a4.w;
        if (!NN) {
            float4 b4 = *(const float4*)(Bb + (long)lr * ldb + (k0 + lk4));
            if (NORMAB) b4 = pairnorm4(b4);
            Bs[lk4 + 0][lr] = b4.x; Bs[lk4 + 1][lr] = b4.y;
            Bs[lk4 + 2][lr] = b4.z; Bs[lk4 + 3][lr] = b4.w;
        } else {
            float4 b4 = *(const float4*)(Bb + (long)(k0 + bkk) * ldb + bn4);
            *(float4*)(&Bs[bkk][bn4]) = b4;
        }
        __syncthreads();
        #pragma unroll
        for (int kk = 0; kk < 16; ++kk) {
            float av0 = As[kk][ty * 4 + 0];
            float av1 = As[kk][ty * 4 + 1];
            float av2 = As[kk][ty * 4 + 2];
            float av3 = As[kk][ty * 4 + 3];
            float bv0 = Bs[kk][tx * 4 + 0];
            float bv1 = Bs[kk][tx * 4 + 1];
            float bv2 = Bs[kk][tx * 4 + 2];
            float bv3 = Bs[kk][tx * 4 + 3];
            acc[0][0] += av0 * bv0; acc[0][1] += av0 * bv1; acc[0][2] += av0 * bv2; acc[0][3] += av0 * bv3;
            acc[1][0] += av1 * bv0; acc[1][1] += av1 * bv1; acc[1][2] += av1 * bv2; acc[1][3] += av1 * bv3;
            acc[2][0] += av2 * bv0; acc[2][1] += av2 * bv1; acc[2][2] += av2 * bv2; acc[2][3] += av2 * bv3;
            acc[3][0] += av3 * bv0; acc[3][1] += av3 * bv1; acc[3][2] += av3 * bv2; acc[3][3] += av3 * bv3;
        }
        __syncthreads();
    }
    float* Cz = C + (long)z * zsC;
    const int mm = m0 + ty * 4, nn = n0 + tx * 4;
    if constexpr (MODE == 0) {
        if constexpr (ATOMIC) {
            #pragma unroll
            for (int i = 0; i < 4; ++i)
                #pragma unroll
                for (int j = 0; j < 4; ++j)
                    atomicAdd(&Cz[(long)(mm + i) * ldc + nn + j], alpha * acc[i][j]);
        } else {
            #pragma unroll
            for (int i = 0; i < 4; ++i) {
                float4 v;
                v.x = alpha * acc[i][0]; v.y = alpha * acc[i][1];
                v.z = alpha * acc[i][2]; v.w = alpha * acc[i][3];
                *(float4*)(Cz + (long)(mm + i) * ldc + nn) = v;
            }
        }
    } else if constexpr (MODE == 1) {
        #pragma unroll
        for (int i = 0; i < 4; ++i) {
            float rsv = alpha * rs[mm + i];
            const float4 b4 = *(const float4*)(base + (long)(mm + i) * ldc + nn);
            float4 v;
            v.x = b4.x + acc[i][0] * rsv; v.y = b4.y + acc[i][1] * rsv;
            v.z = b4.z + acc[i][2] * rsv; v.w = b4.w + acc[i][3] * rsv;
            *(float4*)(Cz + (long)(mm + i) * ldc + nn) = v;
        }
    } else {
        const float* aAz = accA + (long)z * zsAA;
        const float* aBz = accB + (long)z * zsAB;
        float* OTz = OT + (long)z * zsOT;
        #pragma unroll
        for (int i = 0; i < 4; ++i) {
            const float4 a4 = *(const float4*)(aAz + (long)(mm + i) * ldc + nn);
            float4 v;
            v.x = 0.7f * a4.x + 0.3f * alpha * acc[i][0];
            v.y = 0.7f * a4.y + 0.3f * alpha * acc[i][1];
            v.z = 0.7f * a4.z + 0.3f * alpha * acc[i][2];
            v.w = 0.7f * a4.w + 0.3f * alpha * acc[i][3];
            *(float4*)(Cz + (long)(mm + i) * ldc + nn) = v;
            #pragma unroll
            for (int j = 0; j < 4; ++j) {
                long ti = (long)(nn + j) * ldt + (mm + i);
                OTz[ti] = 0.7f * aBz[ti] + 0.3f * alpha * acc[i][j];
            }
        }
    }
}

// ---------------------------------------------------------------------------
// softmax + gate + renorm, one wave per row of TK=NU*64, in place.
// w[q,k] = e_k*eg_k*ag / (ag*sum(e*eg) + l*1e-8), e w.r.t. row max, l=sum e.
// ---------------------------------------------------------------------------
template<int NU>
__global__ void __launch_bounds__(256) softmax_gate_kernel(
    float* __restrict__ P,
    const float* __restrict__ AG,   // (TQ) gate per q-row
    const float* __restrict__ EG,   // (TK) gate per k
    int TQ)
{
    const int row = blockIdx.x * 4 + (threadIdx.x >> 6);
    const int lane = threadIdx.x & 63;
    const int q = row % TQ;
    float* pr = P + (long)row * (NU * 64);
    float r[NU];
    float m = -3.4e38f;
    #pragma unroll
    for (int u = 0; u < NU; ++u) {
        r[u] = pr[lane + 64 * u];
        m = fmaxf(m, r[u]);
    }
    for (int o = 32; o > 0; o >>= 1) m = fmaxf(m, __shfl_xor(m, o));
    float l = 0.0f, se = 0.0f;
    #pragma unroll
    for (int u = 0; u < NU; ++u) {
        float e = __expf(r[u] - m);
        l += e;
        float eg = EG[lane + 64 * u];
        r[u] = e * eg;
        se += r[u];
    }
    for (int o = 32; o > 0; o >>= 1) { l += __shfl_xor(l, o); se += __shfl_xor(se, o); }
    const float ag = AG[q];
    const float f = ag / (ag * se + l * 1e-8f);
    #pragma unroll
    for (int u = 0; u < NU; ++u) pr[lane + 64 * u] = r[u] * f;
}

// ---------------------------------------------------------------------------
// sigmoid(alpha * row-mean), one wave per row.
// ---------------------------------------------------------------------------
__global__ void __launch_bounds__(256) rowmean_sig_kernel(
    const float* __restrict__ X, int len, float invlen,
    const float* __restrict__ alpha_p, float* __restrict__ OUT)
{
    const int row = blockIdx.x * 4 + (threadIdx.x >> 6);
    const int lane = threadIdx.x & 63;
    const float* xr = X + (long)row * len;
    float s = 0.0f;
    for (int k = lane; k < len; k += 64) s += xr[k];
    for (int o = 32; o > 0; o >>= 1) s += __shfl_xor(s, o);
    if (lane == 0) OUT[row] = sigmoidf_((*alpha_p) * s * invlen);
}

#define GEMM_TAIL0 nullptr, nullptr, nullptr, 0L, nullptr, 0L, nullptr, 0L, 0

extern "C" void kernel_launch(void* const* d_in, const int* in_sizes, int n_in,
                              void* d_out, int out_size, void* d_ws, size_t ws_size,
                              hipStream_t stream)
{
    (void)in_sizes; (void)n_in; (void)out_size; (void)ws_size;
    const float* o_micro    = (const float*)d_in[0];
    const float* o_macro    = (const float*)d_in[1];
    const float* r_conv_acc = (const float*)d_in[2];
    const float* r_emer_acc = (const float*)d_in[3];
    const float* ln_u_w = (const float*)d_in[4];
    const float* ln_u_b = (const float*)d_in[5];
    const float* bw_u   = (const float*)d_in[6];
    const float* ln_m_w = (const float*)d_in[7];
    const float* ln_m_b = (const float*)d_in[8];
    const float* bw_m   = (const float*)d_in[9];
    const float* gu_w   = (const float*)d_in[10];
    const float* gu_b   = (const float*)d_in[11];
    const float* gm_w   = (const float*)d_in[12];
    const float* gm_b   = (const float*)d_in[13];
    const float* wq_c   = (const float*)d_in[14];
    const float* wk_c   = (const float*)d_in[15];
    const float* wv_c   = (const float*)d_in[16];
    const float* wo_c   = (const float*)d_in[17];
    const float* wq_e   = (const float*)d_in[18];
    const float* wk_e   = (const float*)d_in[19];
    const float* wv_e   = (const float*)d_in[20];
    const float* wo_e   = (const float*)d_in[21];
    const float* res_alpha = (const float*)d_in[22];

    float* out = (float*)d_out;
    float* out_micro = out;              // (4,2048,1024) 8388608
    float* out_macro = out + 8388608;    // (4,256,1024)  1048576
    float* out_rconv = out + 9437184;    // (4,256,2048)  2097152
    float* out_remer = out + 11534336;   // (4,2048,256)  2097152

    float* ws  = (float*)d_ws;
    float* OU  = ws;              // 8388608  normed micro
    float* P1  = OU + 8388608;    // 8388608  k_conv -> q_emer
    float* VC  = P1 + 8388608;    // 8388608  v_conv
    float* OM  = VC + 8388608;    // 1048576  normed macro
    float* P2  = OM + 1048576;    // 1048576  q_conv -> k_emer
    float* CT1 = P2 + 1048576;    // 1048576  ctx_conv (atomic accum)
    float* VE  = CT1 + 1048576;   // 1048576  v_emer
    float* GU  = VE + 1048576;    // 8192     g_micro
    float* GM  = GU + 8192;       // 1024     g_macro
    float* RCS = GM + 1024;       // 1024     r_conv_scalar
    float* RES = RCS + 1024;      // 8192     r_emer_scalar
    float* CTE = OU;              // ctx_emer reuses OU (dead after q_emer GEMM)
    float* SC  = out_micro;       // per-batch score slab reuses o_micro_new region

    (void)hipMemsetAsync(CT1, 0, 1048576 * sizeof(float), stream);

    // --- balance norms + gates ---
    norm_gate_kernel<<<8192, 256, 0, stream>>>(o_micro, ln_u_w, ln_u_b, bw_u, gu_w, gu_b, OU, GU);
    norm_gate_kernel<<<1024, 256, 0, stream>>>(o_macro, ln_m_w, ln_m_b, bw_m, gm_w, gm_b, OM, GM);

    // --- phase resonance (pair-normalize fused into loads), blend, transpose ---
    gemm_kernel<2, true, false, false><<<dim3(32, 4, 4), 256, 0, stream>>>(
        OM, 262144L, OU, 2097152L, out_rconv, 524288L,
        1024, 1024, 1024, 2048, 1.0f / 512.0f,
        nullptr, nullptr,
        r_conv_acc, 524288L, r_emer_acc, 524288L,
        out_remer, 524288L, 256, 1);

    // --- resonance scalars ---
    rowmean_sig_kernel<<<256, 256, 0, stream>>>(out_rconv, 2048, 1.0f / 2048.0f, res_alpha, RCS);
    rowmean_sig_kernel<<<2048, 256, 0, stream>>>(out_remer, 256, 1.0f / 256.0f, res_alpha, RES);

    // --- conv MHA projections (NT, weights are (N,K) K-contiguous) ---
    gemm_kernel<0, false, false, false><<<dim3(16, 16, 1), 256, 0, stream>>>(
        OM, 0L, wq_c, 0L, P2, 0L, 1024, 1024, 1024, 1024, 1.0f, GEMM_TAIL0, 1);
    gemm_kernel<0, false, false, false><<<dim3(16, 128, 1), 256, 0, stream>>>(
        OU, 0L, wk_c, 0L, P1, 0L, 1024, 1024, 1024, 1024, 1.0f, GEMM_TAIL0, 1);
    gemm_kernel<0, false, false, false><<<dim3(16, 128, 1), 256, 0, stream>>>(
        OU, 0L, wv_c, 0L, VC, 0L, 1024, 1024, 1024, 1024, 1.0f, GEMM_TAIL0, 1);

    // --- conv attention, per batch (scores slab = out_micro region) ---
    for (int b = 0; b < 4; ++b) {
        gemm_kernel<0, false, false, false><<<dim3(32, 4, 16), 256, 0, stream>>>(
            P2 + (long)b * 262144, 64L, P1 + (long)b * 2097152, 64L, SC, 524288L,
            64, 1024, 1024, 2048, 0.125f, GEMM_TAIL0, 1);
        softmax_gate_kernel<32><<<1024, 256, 0, stream>>>(SC, GM + b * 256, GU + b * 2048, 256);
        gemm_kernel<0, false, true, true><<<dim3(1, 4, 64), 256, 0, stream>>>(
            SC, 524288L, VC + (long)b * 2097152, 64L, CT1 + (long)b * 262144, 64L,
            2048, 2048, 1024, 1024, 1.0f, GEMM_TAIL0, 4);
    }

    // --- conv out-proj + residual + r_conv_scalar -> o_macro_new ---
    gemm_kernel<1, false, false, false><<<dim3(16, 16, 1), 256, 0, stream>>>(
        CT1, 0L, wo_c, 0L, out_macro, 0L, 1024, 1024, 1024, 1024, 1.0f,
        o_macro, RCS, nullptr, 0L, nullptr, 0L, nullptr, 0L, 0, 1);

    // --- emer MHA projections ---
    gemm_kernel<0, false, false, false><<<dim3(16, 128, 1), 256, 0, stream>>>(
        OU, 0L, wq_e, 0L, P1, 0L, 1024, 1024, 1024, 1024, 1.0f, GEMM_TAIL0, 1);
    gemm_kernel<0, false, false, false><<<dim3(16, 16, 1), 256, 0, stream>>>(
        OM, 0L, wk_e, 0L, P2, 0L, 1024, 1024, 1024, 1024, 1.0f, GEMM_TAIL0, 1);
    gemm_kernel<0, false, false, false><<<dim3(16, 16, 1), 256, 0, stream>>>(
        OM, 0L, wv_e, 0L, VE, 0L, 1024, 1024, 1024, 1024, 1.0f, GEMM_TAIL0, 1);

    // --- emer attention, per batch ---
    for (int b = 0; b < 4; ++b) {
        gemm_kernel<0, false, false, false><<<dim3(4, 32, 16), 256, 0, stream>>>(
            P1 + (long)b * 2097152, 64L, P2 + (long)b * 262144, 64L, SC, 524288L,
            64, 1024, 1024, 256, 0.125f, GEMM_TAIL0, 1);
        softmax_gate_kernel<4><<<8192, 256, 0, stream>>>(SC, GU + b * 2048, GM + b * 256, 2048);
        gemm_kernel<0, false, true, false><<<dim3(1, 32, 16), 256, 0, stream>>>(
            SC, 524288L, VE + (long)b * 262144, 64L, CTE + (long)b * 2097152, 64L,
            256, 256, 1024, 1024, 1.0f, GEMM_TAIL0, 1);
    }

    // --- emer out-proj + residual + r_emer_scalar -> o_micro_new ---
    gemm_kernel<1, false, false, false><<<dim3(16, 128, 1), 256, 0, stream>>>(
        CTE, 0L, wo_e, 0L, out_micro, 0L, 1024, 1024, 1024, 1024, 1.0f,
        o_micro, RES, nullptr, 0L, nullptr, 0L, nullptr, 0L, 0, 1);
}

// Round 2
// 585.763 us; speedup vs baseline: 3.4540x; 3.4540x over previous
//
#include <hip/hip_runtime.h>
#include <math.h>

// B=4, TU=2048, TM=256, D=1024, H=16, DH=64, PAIRS=512
typedef unsigned short u16;
typedef __attribute__((ext_vector_type(8))) short bf16x8;
typedef __attribute__((ext_vector_type(4))) float f32x4;

__device__ __forceinline__ float sigmoidf_(float x) { return 1.0f / (1.0f + __expf(-x)); }
__device__ __forceinline__ u16 f2bf(float v) {
    union { float f; unsigned u; } x; x.f = v;
    unsigned r = x.u + 0x7fffu + ((x.u >> 16) & 1u);
    return (u16)(r >> 16);
}
__device__ __forceinline__ float bf2f(u16 u) {
    union { unsigned u; float f; } x; x.u = ((unsigned)u) << 16; return x.f;
}

// ---------------------------------------------------------------------------
// balance_norm + gate: one block per row of 1024. bf16 output row + gate.
// ---------------------------------------------------------------------------
__global__ void __launch_bounds__(256) norm_gate_kernel(
    const float* __restrict__ X,
    const float* __restrict__ w, const float* __restrict__ bvec,
    const float* __restrict__ bw_p,
    const float* __restrict__ gw, const float* __restrict__ gb_p,
    u16* __restrict__ OUT, float* __restrict__ G)
{
    const int row = blockIdx.x;
    const int t = threadIdx.x;
    const float* xr = X + (size_t)row * 1024;
    float4 x4 = *(const float4*)(xr + 4 * t);
    __shared__ float sh1[256], sh2[256];
    sh1[t] = x4.x + x4.y + x4.z + x4.w;
    sh2[t] = x4.x * x4.x + x4.y * x4.y + x4.z * x4.z + x4.w * x4.w;
    __syncthreads();
    for (int o = 64; o > 0; o >>= 1) {
        if ((t & 127) < o) sh2[t] += sh2[t + o];
        __syncthreads();
    }
    const float slo = sh2[0], shi = sh2[128];
    for (int o = 128; o > 0; o >>= 1) {
        if (t < o) sh1[t] += sh1[t + o];
        __syncthreads();
    }
    const float mu = sh1[0] * (1.0f / 1024.0f);
    const float var = (slo + shi) * (1.0f / 1024.0f) - mu * mu;
    const float rstd = rsqrtf(var + 1e-6f);
    const float imb = (slo - shi) * (1.0f / 512.0f) * (*bw_p);
    const float corr = (t < 128) ? -imb : imb;
    const int i0 = 4 * t;
    float o0 = (x4.x - mu) * rstd * w[i0 + 0] + bvec[i0 + 0] + corr;
    float o1 = (x4.y - mu) * rstd * w[i0 + 1] + bvec[i0 + 1] + corr;
    float o2 = (x4.z - mu) * rstd * w[i0 + 2] + bvec[i0 + 2] + corr;
    float o3 = (x4.w - mu) * rstd * w[i0 + 3] + bvec[i0 + 3] + corr;
    float gd = o0 * gw[i0 + 0] + o1 * gw[i0 + 1] + o2 * gw[i0 + 2] + o3 * gw[i0 + 3];
    __syncthreads();
    sh1[t] = gd;
    __syncthreads();
    for (int o = 128; o > 0; o >>= 1) {
        if (t < o) sh1[t] += sh1[t + o];
        __syncthreads();
    }
    if (t == 0) G[row] = sigmoidf_(sh1[0] + *gb_p);
    u16 ob[4] = { f2bf(o0), f2bf(o1), f2bf(o2), f2bf(o3) };
    *(uint2*)(OUT + (size_t)row * 1024 + i0) = *(uint2*)ob;
}

// ---------------------------------------------------------------------------
// weight fp32 -> bf16 (8 slots of 1M elements, blockIdx.y selects)
// ---------------------------------------------------------------------------
__global__ void __launch_bounds__(256) wconv_kernel(
    const float* w0, const float* w1, const float* w2, const float* w3,
    const float* w4, const float* w5, const float* w6, const float* w7,
    u16* __restrict__ dst)
{
    const float* s;
    switch (blockIdx.y) {
        case 0: s = w0; break; case 1: s = w1; break;
        case 2: s = w2; break; case 3: s = w3; break;
        case 4: s = w4; break; case 5: s = w5; break;
        case 6: s = w6; break; default: s = w7; break;
    }
    long i = (long)blockIdx.x * 1024 + threadIdx.x * 4;
    float4 v = *(const float4*)(s + i);
    u16 o[4] = { f2bf(v.x), f2bf(v.y), f2bf(v.z), f2bf(v.w) };
    *(uint2*)(dst + (long)blockIdx.y * 1048576 + i) = *(uint2*)o;
}

// generic fp32 -> bf16 (4 el/thread)
__global__ void __launch_bounds__(256) cvt_kernel(const float* __restrict__ S, u16* __restrict__ D)
{
    long i = ((long)blockIdx.x * 256 + threadIdx.x) * 4;
    float4 v = *(const float4*)(S + i);
    u16 o[4] = { f2bf(v.x), f2bf(v.y), f2bf(v.z), f2bf(v.w) };
    *(uint2*)(D + i) = *(uint2*)o;
}

// ---------------------------------------------------------------------------
// pair (phase) normalization on bf16: (x+eps, y+eps)/hypot, 8 el/thread
// ---------------------------------------------------------------------------
__global__ void __launch_bounds__(256) pairnorm_kernel(
    const u16* __restrict__ X, u16* __restrict__ Y, int n8)
{
    int i = blockIdx.x * 256 + threadIdx.x;
    if (i >= n8) return;
    uint4 v = *(const uint4*)(X + (long)i * 8);
    u16 in[8]; *(uint4*)in = v;
    u16 o[8];
    #pragma unroll
    for (int j = 0; j < 4; ++j) {
        float x = bf2f(in[2 * j]) + 1e-8f, y = bf2f(in[2 * j + 1]) + 1e-8f;
        float r = rsqrtf(x * x + y * y);
        o[2 * j] = f2bf(x * r); o[2 * j + 1] = f2bf(y * r);
    }
    *(uint4*)(Y + (long)i * 8) = *(uint4*)o;
}

// ---------------------------------------------------------------------------
// bf16 NT MFMA GEMM: C[m,n] = alpha * sum_k A[m][k]*B[n][k]
// BM=128, BK=32, 256 threads (4 waves, 2x2), per-wave 64 x BN/2.
// EPI 0: bf16 store           1: f32 store
//     2: f32 atomicAdd        3: f32 store base[idx] + acc*rs[m]
//     4: bf16 head-transposed store  (VT[b][h][d][T]; ldt=T)
//     5: resonance blend: C=.7*base+.3*v ; OT[k*ldt+q]=.7*accB+.3*v
// z: slab = z/nsplit (A/B/C offset), ks = z%nsplit K-split.
// ---------------------------------------------------------------------------
template<int BN, int EPI>
__global__ void __launch_bounds__(256) mfma_nt(
    const u16* __restrict__ A, long zA,
    const u16* __restrict__ B, long zB,
    void* __restrict__ C, long zC,
    int K, int lda, int ldb, int ldc, float alpha, int nsplit,
    const float* __restrict__ base, const float* __restrict__ rs,
    const float* __restrict__ accB, float* __restrict__ OT,
    long zOT, int ldt, int l2T, long bstr)
{
    constexpr int NR = BN / 32;
    __shared__ __align__(16) u16 As[128 * 32];
    __shared__ __align__(16) u16 Bs[BN * 32];
    const int t = threadIdx.x;
    const int lane = t & 63, w = t >> 6;
    const int wr = w >> 1, wc = w & 1;
    const int zz = blockIdx.z;
    const int slab = zz / nsplit, ks = zz - slab * nsplit;
    const int kchunk = K / nsplit;
    int k0 = ks * kchunk;
    const int kend = k0 + kchunk;
    const long m0 = (long)blockIdx.y * 128;
    const long n0 = (long)blockIdx.x * BN;
    const u16* Ab = A + zA * slab + m0 * lda;
    const u16* Bb = B + zB * slab + n0 * ldb;
    const int srow = t >> 2, sko = (t & 3) * 8;
    f32x4 acc[4][NR] = {};
    for (; k0 < kend; k0 += 32) {
        const u16* ga = Ab + (long)srow * lda + (k0 + sko);
        __builtin_amdgcn_global_load_lds((const __attribute__((address_space(1))) void*)ga,
            (__attribute__((address_space(3))) void*)(As + w * 512), 16, 0, 0);
        __builtin_amdgcn_global_load_lds((const __attribute__((address_space(1))) void*)(ga + 64L * lda),
            (__attribute__((address_space(3))) void*)(As + 2048 + w * 512), 16, 0, 0);
        const u16* gb = Bb + (long)srow * ldb + (k0 + sko);
        __builtin_amdgcn_global_load_lds((const __attribute__((address_space(1))) void*)gb,
            (__attribute__((address_space(3))) void*)(Bs + w * 512), 16, 0, 0);
        if constexpr (BN == 128) {
            __builtin_amdgcn_global_load_lds((const __attribute__((address_space(1))) void*)(gb + 64L * ldb),
                (__attribute__((address_space(3))) void*)(Bs + 2048 + w * 512), 16, 0, 0);
        }
        __syncthreads();
        bf16x8 af[4], bfr[NR];
        #pragma unroll
        for (int m = 0; m < 4; ++m)
            af[m] = *(const bf16x8*)(As + (wr * 64 + m * 16 + (lane & 15)) * 32 + (lane >> 4) * 8);
        #pragma unroll
        for (int n = 0; n < NR; ++n)
            bfr[n] = *(const bf16x8*)(Bs + (wc * (BN / 2) + n * 16 + (lane & 15)) * 32 + (lane >> 4) * 8);
        #pragma unroll
        for (int m = 0; m < 4; ++m)
            #pragma unroll
            for (int n = 0; n < NR; ++n)
                acc[m][n] = __builtin_amdgcn_mfma_f32_16x16x32_bf16(af[m], bfr[n], acc[m][n], 0, 0, 0);
        __syncthreads();
    }
    const int l15 = lane & 15, l4 = lane >> 4;
    #pragma unroll
    for (int m = 0; m < 4; ++m) {
        #pragma unroll
        for (int n = 0; n < NR; ++n) {
            #pragma unroll
            for (int j = 0; j < 4; ++j) {
                const long grow = m0 + wr * 64 + m * 16 + l4 * 4 + j;
                const long gcol = n0 + wc * (BN / 2) + n * 16 + l15;
                const float v = acc[m][n][j] * alpha;
                if constexpr (EPI == 0) {
                    ((u16*)C)[zC * slab + grow * ldc + gcol] = f2bf(v);
                } else if constexpr (EPI == 1) {
                    ((float*)C)[zC * slab + grow * ldc + gcol] = v;
                } else if constexpr (EPI == 2) {
                    atomicAdd((float*)C + zC * slab + grow * ldc + gcol, v);
                } else if constexpr (EPI == 3) {
                    const long idx = grow * ldc + gcol;
                    ((float*)C)[idx] = base[idx] + v * rs[grow];
                } else if constexpr (EPI == 4) {
                    const long bb = grow >> l2T;
                    const long tt = grow & (ldt - 1);
                    ((u16*)C)[bb * bstr + gcol * (long)ldt + tt] = f2bf(v);
                } else {
                    const long idx = zC * slab + grow * ldc + gcol;
                    ((float*)C)[idx] = 0.7f * base[idx] + 0.3f * v;
                    const long tidx = zOT * slab + gcol * (long)ldt + grow;
                    OT[tidx] = 0.7f * accB[tidx] + 0.3f * v;
                }
            }
        }
    }
}

// ---------------------------------------------------------------------------
// softmax + gate + renorm: f32 scores in, bf16 probs out; one wave per row.
// w[q,k] = e_k*eg_k*ag / (ag*sum(e*eg) + l*1e-8)
// ---------------------------------------------------------------------------
template<int NU>
__global__ void __launch_bounds__(256) softmax_gate_kernel(
    const float* __restrict__ SC, u16* __restrict__ P,
    const float* __restrict__ AG, const float* __restrict__ EG, int qmask)
{
    const int row = blockIdx.x * 4 + (threadIdx.x >> 6);
    const int lane = threadIdx.x & 63;
    const int q = row & qmask;
    const float* pr = SC + (long)row * (NU * 64);
    u16* pw = P + (long)row * (NU * 64);
    float r[NU];
    float m = -3.4e38f;
    #pragma unroll
    for (int u = 0; u < NU; ++u) {
        r[u] = pr[lane + 64 * u];
        m = fmaxf(m, r[u]);
    }
    for (int o = 32; o > 0; o >>= 1) m = fmaxf(m, __shfl_xor(m, o));
    float l = 0.0f, se = 0.0f;
    #pragma unroll
    for (int u = 0; u < NU; ++u) {
        float e = __expf(r[u] - m);
        l += e;
        r[u] = e * EG[lane + 64 * u];
        se += r[u];
    }
    for (int o = 32; o > 0; o >>= 1) { l += __shfl_xor(l, o); se += __shfl_xor(se, o); }
    const float ag = AG[q];
    const float f = ag / (ag * se + l * 1e-8f);
    #pragma unroll
    for (int u = 0; u < NU; ++u) pw[lane + 64 * u] = f2bf(r[u] * f);
}

__global__ void __launch_bounds__(256) rowmean_sig_kernel(
    const float* __restrict__ X, int len, float invlen,
    const float* __restrict__ alpha_p, float* __restrict__ OUT)
{
    const int row = blockIdx.x * 4 + (threadIdx.x >> 6);
    const int lane = threadIdx.x & 63;
    const float* xr = X + (long)row * len;
    float s = 0.0f;
    for (int k = lane; k < len; k += 64) s += xr[k];
    for (int o = 32; o > 0; o >>= 1) s += __shfl_xor(s, o);
    if (lane == 0) OUT[row] = sigmoidf_((*alpha_p) * s * invlen);
}

#define MFMA_TAIL nullptr, nullptr, nullptr, nullptr, 0L, 0, 0, 0L

extern "C" void kernel_launch(void* const* d_in, const int* in_sizes, int n_in,
                              void* d_out, int out_size, void* d_ws, size_t ws_size,
                              hipStream_t stream)
{
    (void)in_sizes; (void)n_in; (void)out_size; (void)ws_size;
    const float* o_micro    = (const float*)d_in[0];
    const float* o_macro    = (const float*)d_in[1];
    const float* r_conv_acc = (const float*)d_in[2];
    const float* r_emer_acc = (const float*)d_in[3];
    const float* ln_u_w = (const float*)d_in[4];
    const float* ln_u_b = (const float*)d_in[5];
    const float* bw_u   = (const float*)d_in[6];
    const float* ln_m_w = (const float*)d_in[7];
    const float* ln_m_b = (const float*)d_in[8];
    const float* bw_m   = (const float*)d_in[9];
    const float* gu_w   = (const float*)d_in[10];
    const float* gu_b   = (const float*)d_in[11];
    const float* gm_w   = (const float*)d_in[12];
    const float* gm_b   = (const float*)d_in[13];
    const float* wq_c   = (const float*)d_in[14];
    const float* wk_c   = (const float*)d_in[15];
    const float* wv_c   = (const float*)d_in[16];
    const float* wo_c   = (const float*)d_in[17];
    const float* wq_e   = (const float*)d_in[18];
    const float* wk_e   = (const float*)d_in[19];
    const float* wv_e   = (const float*)d_in[20];
    const float* wo_e   = (const float*)d_in[21];
    const float* res_alpha = (const float*)d_in[22];

    float* out = (float*)d_out;
    float* out_micro = out;              // (4,2048,1024)
    float* out_macro = out + 8388608;    // (4,256,1024)
    float* out_rconv = out + 9437184;    // (4,256,2048)
    float* out_remer = out + 11534336;   // (4,2048,256)

    // workspace layout (f32 slot offsets; bf16 buffers use 2 el/slot)
    float* ws = (float*)d_ws;
    u16* OUb = (u16*)ws;                       // 8388608 bf16 (normed micro)
    u16* OMb = (u16*)(ws + 4194304);           // 1048576 bf16 (normed macro)
    u16* WB  = (u16*)(ws + 4718592);           // 8 x 1048576 bf16 weights
    u16* Kcb = (u16*)(ws + 8912896);           // conv K (8192x1024) -> later CTe
    u16* VTc = (u16*)(ws + 13107200);          // conv V^T [b][h][64][2048]
    u16* Qeb = (u16*)(ws + 17301504);          // emer Q (8192x1024)
    u16* Qcb = (u16*)(ws + 21495808);          // conv Q (1024x1024) -> later CTb
    u16* Keb = (u16*)(ws + 22020096);          // emer K (1024x1024)
    u16* VTe = (u16*)(ws + 22544384);          // emer V^T [b][h][64][256]
    u16* Pb  = (u16*)(ws + 23068672);          // probs per batch (8.4M bf16); early: PNu
    float* CT = ws + 27262976;                 // conv ctx f32 (4x256x1024); early: PNm
    float* GU = ws + 28311552;                 // 8192
    float* GM = GU + 8192;                     // 1024
    float* RCS = GM + 1024;                    // 1024
    float* RES = RCS + 1024;                   // 8192
    u16* PNu = Pb;
    u16* PNm = (u16*)CT;
    u16* CTb = Qcb;
    u16* CTe = Kcb;
    float* SCf = out_micro;                    // per-batch score slab (8.4M f32)

    // 1. weights -> bf16
    wconv_kernel<<<dim3(1024, 8), 256, 0, stream>>>(wq_c, wk_c, wv_c, wo_c, wq_e, wk_e, wv_e, wo_e, WB);
    // 2. balance norms + gates
    norm_gate_kernel<<<8192, 256, 0, stream>>>(o_micro, ln_u_w, ln_u_b, bw_u, gu_w, gu_b, OUb, GU);
    norm_gate_kernel<<<1024, 256, 0, stream>>>(o_macro, ln_m_w, ln_m_b, bw_m, gm_w, gm_b, OMb, GM);
    // 3. pair-normalize for resonance
    pairnorm_kernel<<<4096, 256, 0, stream>>>(OUb, PNu, 1048576);
    pairnorm_kernel<<<512, 256, 0, stream>>>(OMb, PNm, 131072);
    // 4. resonance GEMM + 0.7/0.3 blend + transposed write
    mfma_nt<128, 5><<<dim3(16, 2, 4), 256, 0, stream>>>(
        PNm, 262144L, PNu, 2097152L, out_rconv, 524288L,
        1024, 1024, 1024, 2048, 1.0f / 512.0f, 1,
        r_conv_acc, nullptr, r_emer_acc, out_remer, 524288L, 256, 0, 0L);
    // 5. resonance scalars
    rowmean_sig_kernel<<<256, 256, 0, stream>>>(out_rconv, 2048, 1.0f / 2048.0f, res_alpha, RCS);
    rowmean_sig_kernel<<<2048, 256, 0, stream>>>(out_remer, 256, 1.0f / 256.0f, res_alpha, RES);
    // 6. projections (NT, weights (N,K) K-contiguous)
    mfma_nt<128, 0><<<dim3(8, 64, 1), 256, 0, stream>>>(OUb, 0L, WB + 1 * 1048576, 0L, Kcb, 0L,
        1024, 1024, 1024, 1024, 1.0f, 1, MFMA_TAIL);
    mfma_nt<128, 4><<<dim3(8, 64, 1), 256, 0, stream>>>(OUb, 0L, WB + 2 * 1048576, 0L, VTc, 0L,
        1024, 1024, 1024, 0, 1.0f, 1, nullptr, nullptr, nullptr, nullptr, 0L, 2048, 11, 2097152L);
    mfma_nt<128, 0><<<dim3(8, 64, 1), 256, 0, stream>>>(OUb, 0L, WB + 4 * 1048576, 0L, Qeb, 0L,
        1024, 1024, 1024, 1024, 1.0f, 1, MFMA_TAIL);
    mfma_nt<128, 0><<<dim3(8, 8, 1), 256, 0, stream>>>(OMb, 0L, WB + 0 * 1048576, 0L, Qcb, 0L,
        1024, 1024, 1024, 1024, 1.0f, 1, MFMA_TAIL);
    mfma_nt<128, 0><<<dim3(8, 8, 1), 256, 0, stream>>>(OMb, 0L, WB + 5 * 1048576, 0L, Keb, 0L,
        1024, 1024, 1024, 1024, 1.0f, 1, MFMA_TAIL);
    mfma_nt<128, 4><<<dim3(8, 8, 1), 256, 0, stream>>>(OMb, 0L, WB + 6 * 1048576, 0L, VTe, 0L,
        1024, 1024, 1024, 0, 1.0f, 1, nullptr, nullptr, nullptr, nullptr, 0L, 256, 8, 262144L);
    // 7. conv ctx accumulator
    (void)hipMemsetAsync(CT, 0, 1048576 * sizeof(float), stream);
    // 8. conv attention per batch
    for (int b = 0; b < 4; ++b) {
        mfma_nt<128, 1><<<dim3(16, 2, 16), 256, 0, stream>>>(
            Qcb + (long)b * 262144, 64L, Kcb + (long)b * 2097152, 64L, SCf, 524288L,
            64, 1024, 1024, 2048, 0.125f, 1, MFMA_TAIL);
        softmax_gate_kernel<32><<<1024, 256, 0, stream>>>(SCf, Pb, GM + b * 256, GU + b * 2048, 255);
        mfma_nt<64, 2><<<dim3(1, 2, 128), 256, 0, stream>>>(
            Pb, 524288L, VTc + (long)b * 2097152, 131072L, CT + (long)b * 262144, 64L,
            2048, 2048, 2048, 1024, 1.0f, 8, MFMA_TAIL);
    }
    // 9-10. conv out-proj + residual + r_conv_scalar -> o_macro_new
    cvt_kernel<<<1024, 256, 0, stream>>>(CT, CTb);
    mfma_nt<128, 3><<<dim3(8, 8, 1), 256, 0, stream>>>(CTb, 0L, WB + 3 * 1048576, 0L, out_macro, 0L,
        1024, 1024, 1024, 1024, 1.0f, 1, o_macro, RCS, nullptr, nullptr, 0L, 0, 0, 0L);
    // 11. emer attention per batch
    for (int b = 0; b < 4; ++b) {
        mfma_nt<128, 1><<<dim3(2, 16, 16), 256, 0, stream>>>(
            Qeb + (long)b * 2097152, 64L, Keb + (long)b * 262144, 64L, SCf, 524288L,
            64, 1024, 1024, 256, 0.125f, 1, MFMA_TAIL);
        softmax_gate_kernel<4><<<8192, 256, 0, stream>>>(SCf, Pb, GU + b * 2048, GM + b * 256, 2047);
        mfma_nt<64, 0><<<dim3(1, 16, 16), 256, 0, stream>>>(
            Pb, 524288L, VTe + (long)b * 262144, 16384L, (void*)(CTe + (long)b * 2097152), 64L,
            256, 256, 256, 1024, 1.0f, 1, MFMA_TAIL);
    }
    // 12. emer out-proj + residual + r_emer_scalar -> o_micro_new
    mfma_nt<128, 3><<<dim3(8, 64, 1), 256, 0, stream>>>(CTe, 0L, WB + 7 * 1048576, 0L, out_micro, 0L,
        1024, 1024, 1024, 1024, 1.0f, 1, o_micro, RES, nullptr, nullptr, 0L, 0, 0, 0L);
}